// Round 1
// baseline (294.041 us; speedup 1.0000x reference)
//
#include <hip/hip_runtime.h>
#include <hip/hip_bf16.h>

// Problem constants (B=4, S=2048, D=1024, fp32 in/out)
#define BB 4
#define SS 2048
#define DD 1024

using bf16   = __bf16;
using bf16x8 = __attribute__((ext_vector_type(8))) __bf16;
using bf16x4 = __attribute__((ext_vector_type(4))) __bf16;
using f32x4  = __attribute__((ext_vector_type(4))) float;

// async global->LDS, 16B per lane. LDS dest = wave-uniform base + lane*16.
__device__ __forceinline__ void gld16(const bf16* g, bf16* l) {
    __builtin_amdgcn_global_load_lds(
        (__attribute__((address_space(1))) void*)(g),
        (__attribute__((address_space(3))) void*)(l),
        16, 0, 0);
}

// ---------------------------------------------------------------------------
// fp32 -> bf16 elementwise convert (vectorized x4)
// ---------------------------------------------------------------------------
__global__ void cvt_bf16_kernel(const float* __restrict__ in, bf16* __restrict__ out, int n4) {
    int i = blockIdx.x * blockDim.x + threadIdx.x;
    if (i >= n4) return;
    float4 v = ((const float4*)in)[i];
    bf16x4 o;
    o[0] = (bf16)v.x; o[1] = (bf16)v.y; o[2] = (bf16)v.z; o[3] = (bf16)v.w;
    ((bf16x4*)out)[i] = o;
}

// ---------------------------------------------------------------------------
// NT GEMM: C[m,n] = sum_k A[m,k] * B[n,k]   (A: MxK row-major, B: NxK row-major)
// 128x128 block tile, BK=32, 4 waves each computing 64x64 (4x4 MFMA 16x16x32).
// global_load_lds (width 16) staging, single-buffered (m97 structure).
// Epilogue supports batched output and column-batch-split store (for V^T).
// ---------------------------------------------------------------------------
template <typename CT>
__global__ __launch_bounds__(256, 2) void gemm_bt(
    const bf16* __restrict__ A, const bf16* __restrict__ B, CT* __restrict__ C,
    int M, int N, int K,
    long batchA, long batchB, long batchC,
    int ldc, int col_shift, long cstride) {
    constexpr int BM = 128, BN = 128, BK = 32;
    __shared__ __attribute__((aligned(16))) bf16 As[BM * BK];
    __shared__ __attribute__((aligned(16))) bf16 Bs[BN * BK];

    const int tid  = threadIdx.x;
    const int lane = tid & 63;
    const int wv   = tid >> 6;       // wave 0..3
    const int l16  = lane & 15;
    const int quad = lane >> 4;
    const int wm   = wv >> 1;        // wave row 0..1
    const int wn   = wv & 1;         // wave col 0..1

    const int m0 = blockIdx.y * BM;
    const int n0 = blockIdx.x * BN;
    const long z = blockIdx.z;
    const bf16* Ab = A + z * batchA;
    const bf16* Bb = B + z * batchB;

    f32x4 acc[4][4] = {};

    for (int kt = 0; kt < K; kt += BK) {
        // stage A tile (128x32 bf16 = 8KB = 512 x 16B chunks; 2 per thread)
#pragma unroll
        for (int j = 0; j < 2; ++j) {
            int ci = j * 256 + wv * 64 + lane;     // chunk index 0..511
            int r  = ci >> 2;                      // row (4 chunks per 64B row)
            int c  = (ci & 3) << 3;                // col in elems
            gld16(Ab + (size_t)(m0 + r) * K + (kt + c),
                  As + (size_t)(j * 256 + wv * 64) * 8);
        }
#pragma unroll
        for (int j = 0; j < 2; ++j) {
            int ci = j * 256 + wv * 64 + lane;
            int r  = ci >> 2;
            int c  = (ci & 3) << 3;
            gld16(Bb + (size_t)(n0 + r) * K + (kt + c),
                  Bs + (size_t)(j * 256 + wv * 64) * 8);
        }
        asm volatile("s_waitcnt vmcnt(0)" ::: "memory");
        __syncthreads();

        // fragments: A[m=l16][k=quad*8+j], B^T rows give B-operand cols
        const bf16* Ap = As + (wm * 64 + l16) * BK + quad * 8;
        const bf16* Bp = Bs + (wn * 64 + l16) * BK + quad * 8;
        bf16x8 af[4], bfr[4];
#pragma unroll
        for (int i = 0; i < 4; ++i) af[i]  = *(const bf16x8*)(Ap + i * 16 * BK);
#pragma unroll
        for (int i = 0; i < 4; ++i) bfr[i] = *(const bf16x8*)(Bp + i * 16 * BK);

#pragma unroll
        for (int i = 0; i < 4; ++i)
#pragma unroll
            for (int j = 0; j < 4; ++j)
                acc[i][j] = __builtin_amdgcn_mfma_f32_16x16x32_bf16(af[i], bfr[j], acc[i][j], 0, 0, 0);
        __syncthreads();
    }

    // epilogue: C/D layout col=lane&15, row=quad*4+reg
    CT* Cb = C + z * batchC;
#pragma unroll
    for (int mi = 0; mi < 4; ++mi) {
#pragma unroll
        for (int ni = 0; ni < 4; ++ni) {
            int colg = n0 + wn * 64 + ni * 16 + l16;
            int cb   = colg >> col_shift;                  // 0 when col_shift=31
            int ccol = colg - (cb << col_shift);
#pragma unroll
            for (int r = 0; r < 4; ++r) {
                int rowg = m0 + wm * 64 + mi * 16 + quad * 4 + r;
                Cb[(long)cb * cstride + (size_t)rowg * ldc + ccol] = (CT)acc[mi][ni][r];
            }
        }
    }
}

// ---------------------------------------------------------------------------
// Row softmax over S=2048 keys, in place on bf16 scores, fused mask*1/sqrt(D).
// One block (256 thr) per row; 8 elems/thread.
// ---------------------------------------------------------------------------
__global__ void softmax_rows(bf16* __restrict__ sc, const float* __restrict__ qmask) {
    const int row = blockIdx.x;          // 0 .. B*S-1
    const int b   = row >> 11;
    const int qi  = row & (SS - 1);
    const float fac = qmask[(b << 11) + qi] * 0.03125f;   // q_mask / sqrt(1024)

    bf16* rp = sc + (size_t)row * SS;
    const int t = threadIdx.x;
    bf16x8 v8 = *(const bf16x8*)(rp + t * 8);

    float v[8];
    float mx = -1e30f;
#pragma unroll
    for (int j = 0; j < 8; ++j) { v[j] = (float)v8[j] * fac; mx = fmaxf(mx, v[j]); }
#pragma unroll
    for (int off = 32; off; off >>= 1) mx = fmaxf(mx, __shfl_xor(mx, off));

    __shared__ float redm[4];
    __shared__ float reds[4];
    const int lane = t & 63, w = t >> 6;
    if (lane == 0) redm[w] = mx;
    __syncthreads();
    mx = fmaxf(fmaxf(redm[0], redm[1]), fmaxf(redm[2], redm[3]));

    float sum = 0.f;
#pragma unroll
    for (int j = 0; j < 8; ++j) { v[j] = __expf(v[j] - mx); sum += v[j]; }
#pragma unroll
    for (int off = 32; off; off >>= 1) sum += __shfl_xor(sum, off);
    if (lane == 0) reds[w] = sum;
    __syncthreads();
    sum = reds[0] + reds[1] + reds[2] + reds[3];

    const float inv = 1.0f / sum;
    bf16x8 o;
#pragma unroll
    for (int j = 0; j < 8; ++j) o[j] = (bf16)(v[j] * inv);
    *(bf16x8*)(rp + t * 8) = o;
}

// ---------------------------------------------------------------------------
extern "C" void kernel_launch(void* const* d_in, const int* in_sizes, int n_in,
                              void* d_out, int out_size, void* d_ws, size_t ws_size,
                              hipStream_t stream) {
    const float* x     = (const float*)d_in[0];
    const float* Wq    = (const float*)d_in[1];
    const float* Wk    = (const float*)d_in[2];
    const float* Wv    = (const float*)d_in[3];
    const float* qmask = (const float*)d_in[4];
    float* out = (float*)d_out;

    const long nx  = (long)BB * SS * DD;   // 8,388,608
    const long nw  = (long)DD * DD;        // 1,048,576
    const long nsc = (long)BB * SS * SS;   // 16,777,216

    bf16* ws  = (bf16*)d_ws;
    bf16* xb  = ws;             // B*S x D   (row-major, K-major)
    bf16* wqb = xb + nx;        // D x D
    bf16* wkb = wqb + nw;
    bf16* wvb = wkb + nw;
    bf16* qb  = wvb + nw;       // B*S x D
    bf16* kb  = qb + nx;        // B*S x D
    bf16* vtb = kb + nx;        // (B, D, S) — V transposed per batch
    bf16* scb = vtb + nx;       // (B, S, S) scores then attn (in place)

    // 1. fp32 -> bf16 conversions
    cvt_bf16_kernel<<<dim3((int)(nx / 4 / 256)), dim3(256), 0, stream>>>(x, xb, (int)(nx / 4));
    cvt_bf16_kernel<<<dim3((int)(nw / 4 / 256)), dim3(256), 0, stream>>>(Wq, wqb, (int)(nw / 4));
    cvt_bf16_kernel<<<dim3((int)(nw / 4 / 256)), dim3(256), 0, stream>>>(Wk, wkb, (int)(nw / 4));
    cvt_bf16_kernel<<<dim3((int)(nw / 4 / 256)), dim3(256), 0, stream>>>(Wv, wvb, (int)(nw / 4));

    // 2. Q = x @ Wq^T, K = x @ Wk^T   (M=8192, N=1024, K=1024)
    gemm_bt<bf16><<<dim3(DD / 128, (BB * SS) / 128, 1), 256, 0, stream>>>(
        xb, wqb, qb, BB * SS, DD, DD, 0, 0, 0, DD, 31, 0);
    gemm_bt<bf16><<<dim3(DD / 128, (BB * SS) / 128, 1), 256, 0, stream>>>(
        xb, wkb, kb, BB * SS, DD, DD, 0, 0, 0, DD, 31, 0);

    // 3. V^T = Wv @ x^T  (M=1024 rows=d, N=8192 cols=s) -> (B, D, S) via col split
    gemm_bt<bf16><<<dim3((BB * SS) / 128, DD / 128, 1), 256, 0, stream>>>(
        wvb, xb, vtb, DD, BB * SS, DD, 0, 0, 0, SS, 11, (long)DD * SS);

    // 4. scores = Q @ K^T per batch (raw, unscaled), bf16
    gemm_bt<bf16><<<dim3(SS / 128, SS / 128, BB), 256, 0, stream>>>(
        qb, kb, scb, SS, SS, DD, (long)SS * DD, (long)SS * DD, (long)SS * SS, SS, 31, 0);

    // 5. softmax with fused q_mask/sqrt(D), in place
    softmax_rows<<<dim3(BB * SS), dim3(256), 0, stream>>>(scb, qmask);

    // 6. out = attn @ V  == attn(MxK) . vt(NxK)^T, fp32 out
    gemm_bt<float><<<dim3(DD / 128, SS / 128, BB), 256, 0, stream>>>(
        scb, vtb, out, SS, DD, SS, (long)SS * SS, (long)DD * SS, (long)SS * DD, DD, 31, 0);
}

// Round 2
// 274.380 us; speedup vs baseline: 1.0717x; 1.0717x over previous
//
#include <hip/hip_runtime.h>
#include <hip/hip_bf16.h>

// Problem constants (B=4, S=2048, D=1024, fp32 in/out)
#define BB 4
#define SS 2048
#define DD 1024

using bf16   = __bf16;
using bf16x8 = __attribute__((ext_vector_type(8))) __bf16;
using bf16x4 = __attribute__((ext_vector_type(4))) __bf16;
using f32x4  = __attribute__((ext_vector_type(4))) float;

// async global->LDS, 16B per lane. LDS dest = wave-uniform base + lane*16.
__device__ __forceinline__ void gld16(const bf16* g, bf16* l) {
    __builtin_amdgcn_global_load_lds(
        (__attribute__((address_space(1))) void*)(g),
        (__attribute__((address_space(3))) void*)(l),
        16, 0, 0);
}

// ---------------------------------------------------------------------------
// fp32 -> bf16 elementwise convert (vectorized x4)
// ---------------------------------------------------------------------------
__global__ void cvt_bf16_kernel(const float* __restrict__ in, bf16* __restrict__ out, int n4) {
    int i = blockIdx.x * blockDim.x + threadIdx.x;
    if (i >= n4) return;
    float4 v = ((const float4*)in)[i];
    bf16x4 o;
    o[0] = (bf16)v.x; o[1] = (bf16)v.y; o[2] = (bf16)v.z; o[3] = (bf16)v.w;
    ((bf16x4*)out)[i] = o;
}

// 3 weights (each n4 float4 chunks) in one launch; wq/wk/wv outputs contiguous.
__global__ void cvt3_bf16_kernel(const float* __restrict__ w0, const float* __restrict__ w1,
                                 const float* __restrict__ w2, bf16* __restrict__ out, int n4) {
    int i = blockIdx.x * blockDim.x + threadIdx.x;
    int seg = i / n4;           // 0,1,2 — wave-uniform within a block (n4 % 256 == 0)
    int j = i - seg * n4;
    const float* src = (seg == 0) ? w0 : (seg == 1) ? w1 : w2;
    float4 v = ((const float4*)src)[j];
    bf16x4 o;
    o[0] = (bf16)v.x; o[1] = (bf16)v.y; o[2] = (bf16)v.z; o[3] = (bf16)v.w;
    ((bf16x4*)(out + (size_t)seg * n4 * 4))[j] = o;
}

// ---------------------------------------------------------------------------
// NT GEMM: C[m,n] = sum_k A[m,k] * B[n,k]   (A: MxK row-major, B: NxK row-major)
// 128x128 block tile, BK=32, 4 waves each computing 64x64 (4x4 MFMA 16x16x32).
// global_load_lds (width 16) staging, single-buffered (m97 structure).
// __launch_bounds__(256,4): 4 waves/EU -> 4 blocks/CU (regs ~120/wave, LDS 16KB).
// ---------------------------------------------------------------------------
template <typename CT>
__global__ __launch_bounds__(256, 4) void gemm_bt(
    const bf16* __restrict__ A, const bf16* __restrict__ B, CT* __restrict__ C,
    int M, int N, int K,
    long batchA, long batchB, long batchC,
    int ldc, int col_shift, long cstride) {
    constexpr int BM = 128, BN = 128, BK = 32;
    __shared__ __attribute__((aligned(16))) bf16 As[BM * BK];
    __shared__ __attribute__((aligned(16))) bf16 Bs[BN * BK];

    const int tid  = threadIdx.x;
    const int lane = tid & 63;
    const int wv   = tid >> 6;       // wave 0..3
    const int l16  = lane & 15;
    const int quad = lane >> 4;
    const int wm   = wv >> 1;        // wave row 0..1
    const int wn   = wv & 1;         // wave col 0..1

    const int m0 = blockIdx.y * BM;
    const int n0 = blockIdx.x * BN;
    const long z = blockIdx.z;
    const bf16* Ab = A + z * batchA;
    const bf16* Bb = B + z * batchB;

    f32x4 acc[4][4] = {};

    for (int kt = 0; kt < K; kt += BK) {
        // stage A tile (128x32 bf16 = 8KB = 512 x 16B chunks; 2 per thread)
#pragma unroll
        for (int j = 0; j < 2; ++j) {
            int ci = j * 256 + wv * 64 + lane;     // chunk index 0..511
            int r  = ci >> 2;                      // row (4 chunks per 64B row)
            int c  = (ci & 3) << 3;                // col in elems
            gld16(Ab + (size_t)(m0 + r) * K + (kt + c),
                  As + (size_t)(j * 256 + wv * 64) * 8);
        }
#pragma unroll
        for (int j = 0; j < 2; ++j) {
            int ci = j * 256 + wv * 64 + lane;
            int r  = ci >> 2;
            int c  = (ci & 3) << 3;
            gld16(Bb + (size_t)(n0 + r) * K + (kt + c),
                  Bs + (size_t)(j * 256 + wv * 64) * 8);
        }
        asm volatile("s_waitcnt vmcnt(0)" ::: "memory");
        __syncthreads();

        // fragments: A[m=l16][k=quad*8+j], B^T rows give B-operand cols
        const bf16* Ap = As + (wm * 64 + l16) * BK + quad * 8;
        const bf16* Bp = Bs + (wn * 64 + l16) * BK + quad * 8;
        bf16x8 af[4], bfr[4];
#pragma unroll
        for (int i = 0; i < 4; ++i) af[i]  = *(const bf16x8*)(Ap + i * 16 * BK);
#pragma unroll
        for (int i = 0; i < 4; ++i) bfr[i] = *(const bf16x8*)(Bp + i * 16 * BK);

#pragma unroll
        for (int i = 0; i < 4; ++i)
#pragma unroll
            for (int j = 0; j < 4; ++j)
                acc[i][j] = __builtin_amdgcn_mfma_f32_16x16x32_bf16(af[i], bfr[j], acc[i][j], 0, 0, 0);
        __syncthreads();
    }

    // epilogue: C/D layout col=lane&15, row=quad*4+reg
    CT* Cb = C + z * batchC;
#pragma unroll
    for (int mi = 0; mi < 4; ++mi) {
#pragma unroll
        for (int ni = 0; ni < 4; ++ni) {
            int colg = n0 + wn * 64 + ni * 16 + l16;
            int cb   = colg >> col_shift;                  // 0 when col_shift=31
            int ccol = colg - (cb << col_shift);
#pragma unroll
            for (int r = 0; r < 4; ++r) {
                int rowg = m0 + wm * 64 + mi * 16 + quad * 4 + r;
                Cb[(long)cb * cstride + (size_t)rowg * ldc + ccol] = (CT)acc[mi][ni][r];
            }
        }
    }
}

// ---------------------------------------------------------------------------
// Row softmax over S=2048 keys, in place on bf16 scores, fused mask*1/sqrt(D).
// One block (256 thr) per row; 8 elems/thread.
// ---------------------------------------------------------------------------
__global__ void softmax_rows(bf16* __restrict__ sc, const float* __restrict__ qmask) {
    const int row = blockIdx.x;          // 0 .. B*S-1
    const float fac = qmask[row] * 0.03125f;   // q_mask / sqrt(1024)

    bf16* rp = sc + (size_t)row * SS;
    const int t = threadIdx.x;
    bf16x8 v8 = *(const bf16x8*)(rp + t * 8);

    float v[8];
    float mx = -1e30f;
#pragma unroll
    for (int j = 0; j < 8; ++j) { v[j] = (float)v8[j] * fac; mx = fmaxf(mx, v[j]); }
#pragma unroll
    for (int off = 32; off; off >>= 1) mx = fmaxf(mx, __shfl_xor(mx, off));

    __shared__ float redm[4];
    __shared__ float reds[4];
    const int lane = t & 63, w = t >> 6;
    if (lane == 0) redm[w] = mx;
    __syncthreads();
    mx = fmaxf(fmaxf(redm[0], redm[1]), fmaxf(redm[2], redm[3]));

    float sum = 0.f;
#pragma unroll
    for (int j = 0; j < 8; ++j) { v[j] = __expf(v[j] - mx); sum += v[j]; }
#pragma unroll
    for (int off = 32; off; off >>= 1) sum += __shfl_xor(sum, off);
    if (lane == 0) reds[w] = sum;
    __syncthreads();
    sum = reds[0] + reds[1] + reds[2] + reds[3];

    const float inv = 1.0f / sum;
    bf16x8 o;
#pragma unroll
    for (int j = 0; j < 8; ++j) o[j] = (bf16)(v[j] * inv);
    *(bf16x8*)(rp + t * 8) = o;
}

// ---------------------------------------------------------------------------
extern "C" void kernel_launch(void* const* d_in, const int* in_sizes, int n_in,
                              void* d_out, int out_size, void* d_ws, size_t ws_size,
                              hipStream_t stream) {
    const float* x     = (const float*)d_in[0];
    const float* Wq    = (const float*)d_in[1];
    const float* Wk    = (const float*)d_in[2];
    const float* Wv    = (const float*)d_in[3];
    const float* qmask = (const float*)d_in[4];
    float* out = (float*)d_out;

    const long nx  = (long)BB * SS * DD;   // 8,388,608
    const long nw  = (long)DD * DD;        // 1,048,576

    bf16* ws  = (bf16*)d_ws;
    bf16* xb  = ws;             // B*S x D   (row-major, K-major)
    bf16* wqb = xb + nx;        // D x D   (wq, wk, wv contiguous)
    bf16* wkb = wqb + nw;
    bf16* wvb = wkb + nw;
    bf16* qb  = wvb + nw;       // B*S x D  (q, k contiguous)
    bf16* kb  = qb + nx;        // B*S x D
    bf16* vtb = kb + nx;        // (B, D, S) — V transposed per batch
    bf16* scb = vtb + nx;       // (B, S, S) scores then attn (in place)

    // 1. fp32 -> bf16 conversions (x; then all 3 weights in one launch)
    cvt_bf16_kernel<<<dim3((int)(nx / 4 / 256)), dim3(256), 0, stream>>>(x, xb, (int)(nx / 4));
    cvt3_bf16_kernel<<<dim3((int)(3 * nw / 4 / 256)), dim3(256), 0, stream>>>(
        Wq, Wk, Wv, wqb, (int)(nw / 4));

    // 2. Q = x @ Wq^T and K = x @ Wk^T in one batched dispatch (z=2)
    gemm_bt<bf16><<<dim3(DD / 128, (BB * SS) / 128, 2), 256, 0, stream>>>(
        xb, wqb, qb, BB * SS, DD, DD, 0, nw, nx, DD, 31, 0);

    // 3. V^T = Wv @ x^T  (M=1024 rows=d, N=8192 cols=s) -> (B, D, S) via col split
    gemm_bt<bf16><<<dim3((BB * SS) / 128, DD / 128, 1), 256, 0, stream>>>(
        wvb, xb, vtb, DD, BB * SS, DD, 0, 0, 0, SS, 11, (long)DD * SS);

    // 4. scores = Q @ K^T per batch (raw, unscaled), bf16
    gemm_bt<bf16><<<dim3(SS / 128, SS / 128, BB), 256, 0, stream>>>(
        qb, kb, scb, SS, SS, DD, (long)SS * DD, (long)SS * DD, (long)SS * SS, SS, 31, 0);

    // 5. softmax with fused q_mask/sqrt(D), in place
    softmax_rows<<<dim3(BB * SS), dim3(256), 0, stream>>>(scb, qmask);

    // 6. out = attn @ V  == attn(MxK) . vt(NxK)^T, fp32 out
    gemm_bt<float><<<dim3(DD / 128, SS / 128, BB), 256, 0, stream>>>(
        scb, vtb, out, SS, DD, SS, (long)SS * SS, (long)DD * SS, (long)SS * DD, DD, 31, 0);
}

// Round 3
// 246.531 us; speedup vs baseline: 1.1927x; 1.1130x over previous
//
#include <hip/hip_runtime.h>
#include <hip/hip_bf16.h>

// Problem constants (B=4, S=2048, D=1024, fp32 in/out)
#define BB 4
#define SS 2048
#define DD 1024

using bf16   = __bf16;
using bf16x8 = __attribute__((ext_vector_type(8))) __bf16;
using bf16x4 = __attribute__((ext_vector_type(4))) __bf16;
using f32x4  = __attribute__((ext_vector_type(4))) float;
using i32x4  = __attribute__((ext_vector_type(4))) int;
using i32x8  = __attribute__((ext_vector_type(8))) int;

struct f8_t { unsigned char b; };

// async global->LDS, 16B per lane. LDS dest = wave-uniform base + lane*16.
__device__ __forceinline__ void gld16(const void* g, void* l) {
    __builtin_amdgcn_global_load_lds(
        (const __attribute__((address_space(1))) void*)(g),
        (__attribute__((address_space(3))) void*)(l),
        16, 0, 0);
}

__device__ __forceinline__ void store1(bf16* p, float v)  { *p = (bf16)v; }
__device__ __forceinline__ void store1(float* p, float v) { *p = v; }
__device__ __forceinline__ void store1(f8_t* p, float v)  {
    p->b = (unsigned char)(__builtin_amdgcn_cvt_pk_fp8_f32(v, v, 0, false) & 0xff);
}

// ---------------------------------------------------------------------------
// x: fp32 -> bf16 AND fp8(e4m3) in one pass (8 elems/thread)
// ---------------------------------------------------------------------------
__global__ void cvt_x_kernel(const float* __restrict__ x, bf16* __restrict__ xb,
                             unsigned char* __restrict__ x8, int n8) {
    int i = blockIdx.x * blockDim.x + threadIdx.x;
    if (i >= n8) return;
    float4 a = ((const float4*)x)[2 * i];
    float4 b = ((const float4*)x)[2 * i + 1];
    bf16x8 o;
    o[0]=(bf16)a.x; o[1]=(bf16)a.y; o[2]=(bf16)a.z; o[3]=(bf16)a.w;
    o[4]=(bf16)b.x; o[5]=(bf16)b.y; o[6]=(bf16)b.z; o[7]=(bf16)b.w;
    ((bf16x8*)xb)[i] = o;
    int lo = __builtin_amdgcn_cvt_pk_fp8_f32(a.x, a.y, 0, false);
    lo     = __builtin_amdgcn_cvt_pk_fp8_f32(a.z, a.w, lo, true);
    int hi = __builtin_amdgcn_cvt_pk_fp8_f32(b.x, b.y, 0, false);
    hi     = __builtin_amdgcn_cvt_pk_fp8_f32(b.z, b.w, hi, true);
    ((int2*)x8)[i] = make_int2(lo, hi);
}

// Wq,Wk -> fp8 (contiguous), Wv -> bf16, one launch. n8 = nw/8.
__global__ void cvt_w_kernel(const float* __restrict__ Wq, const float* __restrict__ Wk,
                             const float* __restrict__ Wv,
                             unsigned char* __restrict__ w8, bf16* __restrict__ wvb, int n8) {
    int i = blockIdx.x * blockDim.x + threadIdx.x;
    int seg = i / n8;            // wave-uniform (n8 % 256 == 0)
    int j = i - seg * n8;
    if (seg < 2) {
        const float* src = seg ? Wk : Wq;
        float4 a = ((const float4*)src)[2 * j];
        float4 b = ((const float4*)src)[2 * j + 1];
        int lo = __builtin_amdgcn_cvt_pk_fp8_f32(a.x, a.y, 0, false);
        lo     = __builtin_amdgcn_cvt_pk_fp8_f32(a.z, a.w, lo, true);
        int hi = __builtin_amdgcn_cvt_pk_fp8_f32(b.x, b.y, 0, false);
        hi     = __builtin_amdgcn_cvt_pk_fp8_f32(b.z, b.w, hi, true);
        ((int2*)(w8 + (size_t)seg * n8 * 8))[j] = make_int2(lo, hi);
    } else {
        float4 a = ((const float4*)Wv)[2 * j];
        float4 b = ((const float4*)Wv)[2 * j + 1];
        bf16x8 o;
        o[0]=(bf16)a.x; o[1]=(bf16)a.y; o[2]=(bf16)a.z; o[3]=(bf16)a.w;
        o[4]=(bf16)b.x; o[5]=(bf16)b.y; o[6]=(bf16)b.z; o[7]=(bf16)b.w;
        ((bf16x8*)wvb)[j] = o;
    }
}

// ---------------------------------------------------------------------------
// bf16 NT GEMM: C[m,n] = sum_k A[m,k]*B[n,k]. 128x128x32 tile, m97 structure.
// LDS XOR-4 source-swizzle: row r chunk c (16B) lives at slot r*4 + (c^(r&3)).
// Fixes the 4-way fragment-read bank conflict (phase group spans 16 banks @2-way).
// ---------------------------------------------------------------------------
template <typename CT>
__global__ __launch_bounds__(256, 4) void gemm_bt(
    const bf16* __restrict__ A, const bf16* __restrict__ B, CT* __restrict__ C,
    int M, int N, int K,
    long batchA, long batchB, long batchC,
    int ldc, int col_shift, long cstride) {
    constexpr int BM = 128, BN = 128, BK = 32;
    __shared__ __attribute__((aligned(16))) bf16 As[BM * BK];
    __shared__ __attribute__((aligned(16))) bf16 Bs[BN * BK];

    const int tid  = threadIdx.x;
    const int lane = tid & 63;
    const int wv   = tid >> 6;
    const int l16  = lane & 15;
    const int quad = lane >> 4;
    const int wm   = wv >> 1;
    const int wn   = wv & 1;

    const int m0 = blockIdx.y * BM;
    const int n0 = blockIdx.x * BN;
    const long z = blockIdx.z;
    const bf16* Ab = A + z * batchA;
    const bf16* Bb = B + z * batchB;

    const int s0 = quad ^ (l16 & 3);   // swizzled chunk for fragment reads

    f32x4 acc[4][4] = {};

    for (int kt = 0; kt < K; kt += BK) {
#pragma unroll
        for (int j = 0; j < 2; ++j) {
            int slot = j * 256 + wv * 64 + lane;   // 0..511
            int r  = slot >> 2;
            int c  = (slot & 3) ^ (r & 3);         // source chunk (XOR swizzle)
            gld16(Ab + (size_t)(m0 + r) * K + (kt + c * 8),
                  As + (size_t)(j * 256 + wv * 64) * 8);
        }
#pragma unroll
        for (int j = 0; j < 2; ++j) {
            int slot = j * 256 + wv * 64 + lane;
            int r  = slot >> 2;
            int c  = (slot & 3) ^ (r & 3);
            gld16(Bb + (size_t)(n0 + r) * K + (kt + c * 8),
                  Bs + (size_t)(j * 256 + wv * 64) * 8);
        }
        asm volatile("s_waitcnt vmcnt(0)" ::: "memory");
        __syncthreads();

        const bf16* Ap = As + (wm * 64 + l16) * BK + s0 * 8;
        const bf16* Bp = Bs + (wn * 64 + l16) * BK + s0 * 8;
        bf16x8 af[4], bfr[4];
#pragma unroll
        for (int i = 0; i < 4; ++i) af[i]  = *(const bf16x8*)(Ap + i * 16 * BK);
#pragma unroll
        for (int i = 0; i < 4; ++i) bfr[i] = *(const bf16x8*)(Bp + i * 16 * BK);

#pragma unroll
        for (int i = 0; i < 4; ++i)
#pragma unroll
            for (int j = 0; j < 4; ++j)
                acc[i][j] = __builtin_amdgcn_mfma_f32_16x16x32_bf16(af[i], bfr[j], acc[i][j], 0, 0, 0);
        __syncthreads();
    }

    // epilogue: C/D layout col=lane&15, row=quad*4+reg
    CT* Cb = C + z * batchC;
#pragma unroll
    for (int mi = 0; mi < 4; ++mi) {
#pragma unroll
        for (int ni = 0; ni < 4; ++ni) {
            int colg = n0 + wn * 64 + ni * 16 + l16;
            int cb   = colg >> col_shift;
            int ccol = colg - (cb << col_shift);
#pragma unroll
            for (int r = 0; r < 4; ++r) {
                int rowg = m0 + wm * 64 + mi * 16 + quad * 4 + r;
                store1(Cb + (long)cb * cstride + (size_t)rowg * ldc + ccol, acc[mi][ni][r]);
            }
        }
    }
}

// ---------------------------------------------------------------------------
// fp8 (e4m3) NT GEMM via MX-scaled MFMA 16x16x128, unit scales. BK=128.
// LDS XOR-8 swizzle: row r chunk c (16B of 8/row) at slot r*8 + (c^(r&7))
// -> fragment reads fully conflict-free (would be 16-way unswizzled).
// ---------------------------------------------------------------------------
template <typename CT>
__global__ __launch_bounds__(256, 3) void gemm_f8(
    const unsigned char* __restrict__ A, const unsigned char* __restrict__ B,
    CT* __restrict__ C, int M, int N, int K,
    long batchA, long batchB, long batchC, int ldc) {
    constexpr int BM = 128, BN = 128, BK = 128;
    __shared__ __attribute__((aligned(16))) unsigned char As[BM * BK];
    __shared__ __attribute__((aligned(16))) unsigned char Bs[BN * BK];

    const int tid  = threadIdx.x;
    const int lane = tid & 63;
    const int wv   = tid >> 6;
    const int l16  = lane & 15;
    const int quad = lane >> 4;
    const int wm   = wv >> 1;
    const int wn   = wv & 1;

    const int m0 = blockIdx.y * BM;
    const int n0 = blockIdx.x * BN;
    const long z = blockIdx.z;
    const unsigned char* Ab = A + z * batchA;
    const unsigned char* Bb = B + z * batchB;

    const int sA = (2 * quad) ^ (l16 & 7);   // swizzled chunk (low 16B of frag)

    f32x4 acc[4][4] = {};

    for (int kt = 0; kt < K; kt += BK) {
        // stage A,B tiles: 128 rows x 128B = 1024 chunks each; 4/thread/operand
#pragma unroll
        for (int j = 0; j < 4; ++j) {
            int slot = j * 256 + wv * 64 + lane;   // 0..1023
            int r = slot >> 3;
            int c = (slot & 7) ^ (r & 7);
            gld16(Ab + (size_t)(m0 + r) * K + (kt + c * 16),
                  As + (size_t)(j * 256 + wv * 64) * 16);
        }
#pragma unroll
        for (int j = 0; j < 4; ++j) {
            int slot = j * 256 + wv * 64 + lane;
            int r = slot >> 3;
            int c = (slot & 7) ^ (r & 7);
            gld16(Bb + (size_t)(n0 + r) * K + (kt + c * 16),
                  Bs + (size_t)(j * 256 + wv * 64) * 16);
        }
        asm volatile("s_waitcnt vmcnt(0)" ::: "memory");
        __syncthreads();

        // fragments: row = l16 (+tile offsets), k-block = quad (32 bytes)
        i32x8 af[4], bfr[4];
#pragma unroll
        for (int i = 0; i < 4; ++i) {
            int r = wm * 64 + i * 16 + l16;
            i32x4 p0 = *(const i32x4*)(As + r * 128 + sA * 16);
            i32x4 p1 = *(const i32x4*)(As + r * 128 + (sA ^ 1) * 16);
            af[i][0]=p0[0]; af[i][1]=p0[1]; af[i][2]=p0[2]; af[i][3]=p0[3];
            af[i][4]=p1[0]; af[i][5]=p1[1]; af[i][6]=p1[2]; af[i][7]=p1[3];
        }
#pragma unroll
        for (int i = 0; i < 4; ++i) {
            int r = wn * 64 + i * 16 + l16;
            i32x4 p0 = *(const i32x4*)(Bs + r * 128 + sA * 16);
            i32x4 p1 = *(const i32x4*)(Bs + r * 128 + (sA ^ 1) * 16);
            bfr[i][0]=p0[0]; bfr[i][1]=p0[1]; bfr[i][2]=p0[2]; bfr[i][3]=p0[3];
            bfr[i][4]=p1[0]; bfr[i][5]=p1[1]; bfr[i][6]=p1[2]; bfr[i][7]=p1[3];
        }

#pragma unroll
        for (int i = 0; i < 4; ++i)
#pragma unroll
            for (int j = 0; j < 4; ++j)
                acc[i][j] = __builtin_amdgcn_mfma_scale_f32_16x16x128_f8f6f4(
                    af[i], bfr[j], acc[i][j], 0, 0, 0, 127, 0, 127);
        __syncthreads();
    }

    CT* Cb = C + z * batchC;
#pragma unroll
    for (int mi = 0; mi < 4; ++mi) {
#pragma unroll
        for (int ni = 0; ni < 4; ++ni) {
            int colg = n0 + wn * 64 + ni * 16 + l16;
#pragma unroll
            for (int r = 0; r < 4; ++r) {
                int rowg = m0 + wm * 64 + mi * 16 + quad * 4 + r;
                store1(Cb + (size_t)rowg * ldc + colg, acc[mi][ni][r]);
            }
        }
    }
}

// ---------------------------------------------------------------------------
// Row softmax over S=2048 keys, in place on bf16 scores, fused mask*1/sqrt(D).
// ---------------------------------------------------------------------------
__global__ void softmax_rows(bf16* __restrict__ sc, const float* __restrict__ qmask) {
    const int row = blockIdx.x;
    const float fac = qmask[row] * 0.03125f;   // q_mask / sqrt(1024)

    bf16* rp = sc + (size_t)row * SS;
    const int t = threadIdx.x;
    bf16x8 v8 = *(const bf16x8*)(rp + t * 8);

    float v[8];
    float mx = -1e30f;
#pragma unroll
    for (int j = 0; j < 8; ++j) { v[j] = (float)v8[j] * fac; mx = fmaxf(mx, v[j]); }
#pragma unroll
    for (int off = 32; off; off >>= 1) mx = fmaxf(mx, __shfl_xor(mx, off));

    __shared__ float redm[4];
    __shared__ float reds[4];
    const int lane = t & 63, w = t >> 6;
    if (lane == 0) redm[w] = mx;
    __syncthreads();
    mx = fmaxf(fmaxf(redm[0], redm[1]), fmaxf(redm[2], redm[3]));

    float sum = 0.f;
#pragma unroll
    for (int j = 0; j < 8; ++j) { v[j] = __expf(v[j] - mx); sum += v[j]; }
#pragma unroll
    for (int off = 32; off; off >>= 1) sum += __shfl_xor(sum, off);
    if (lane == 0) reds[w] = sum;
    __syncthreads();
    sum = reds[0] + reds[1] + reds[2] + reds[3];

    const float inv = 1.0f / sum;
    bf16x8 o;
#pragma unroll
    for (int j = 0; j < 8; ++j) o[j] = (bf16)(v[j] * inv);
    *(bf16x8*)(rp + t * 8) = o;
}

// ---------------------------------------------------------------------------
extern "C" void kernel_launch(void* const* d_in, const int* in_sizes, int n_in,
                              void* d_out, int out_size, void* d_ws, size_t ws_size,
                              hipStream_t stream) {
    const float* x     = (const float*)d_in[0];
    const float* Wq    = (const float*)d_in[1];
    const float* Wk    = (const float*)d_in[2];
    const float* Wv    = (const float*)d_in[3];
    const float* qmask = (const float*)d_in[4];
    float* out = (float*)d_out;

    const long nx = (long)BB * SS * DD;   // 8,388,608
    const long nw = (long)DD * DD;        // 1,048,576

    // workspace layout (bytes)
    unsigned char* ws = (unsigned char*)d_ws;
    bf16* xb  = (bf16*)ws;                          // x bf16        (16.8 MB)
    bf16* wvb = xb + nx;                            // Wv bf16       (2 MB)
    bf16* vtb = wvb + nw;                           // V^T bf16 (B,D,S) (16.8 MB)
    bf16* scb = vtb + nx;                           // scores bf16   (67 MB)
    unsigned char* x8  = (unsigned char*)(scb + (long)BB * SS * SS);  // x fp8 (8.4 MB)
    unsigned char* w8  = x8 + nx;                   // Wq,Wk fp8     (2 MB)
    f8_t* qk8 = (f8_t*)(w8 + 2 * nw);               // Q,K fp8       (16.8 MB)

    // 1. conversions
    cvt_x_kernel<<<dim3((int)(nx / 8 / 256)), dim3(256), 0, stream>>>(x, xb, x8, (int)(nx / 8));
    cvt_w_kernel<<<dim3((int)(3 * nw / 8 / 256)), dim3(256), 0, stream>>>(
        Wq, Wk, Wv, w8, wvb, (int)(nw / 8));

    // 2. Q = x@Wq^T, K = x@Wk^T — fp8 MX GEMM, batched z=2, fp8 output
    gemm_f8<f8_t><<<dim3(DD / 128, (BB * SS) / 128, 2), 256, 0, stream>>>(
        x8, w8, qk8, BB * SS, DD, DD, 0, nw, nx, DD);

    // 3. V^T = Wv @ x^T -> (B, D, S), bf16 GEMM with col-batch-split store
    gemm_bt<bf16><<<dim3((BB * SS) / 128, DD / 128, 1), 256, 0, stream>>>(
        wvb, xb, vtb, DD, BB * SS, DD, 0, 0, 0, SS, 11, (long)DD * SS);

    // 4. scores = Q @ K^T per batch — fp8 MX GEMM, bf16 output
    gemm_f8<bf16><<<dim3(SS / 128, SS / 128, BB), 256, 0, stream>>>(
        (unsigned char*)qk8, (unsigned char*)qk8 + nx, scb,
        SS, SS, DD, (long)SS * DD, (long)SS * DD, (long)SS * SS, SS);

    // 5. softmax with fused q_mask/sqrt(D), in place
    softmax_rows<<<dim3(BB * SS), dim3(256), 0, stream>>>(scb, qmask);

    // 6. out = attn @ V (bf16 GEMM, fp32 out)
    gemm_bt<float><<<dim3(DD / 128, SS / 128, BB), 256, 0, stream>>>(
        scb, vtb, out, SS, DD, SS, (long)SS * SS, (long)DD * SS, (long)SS * DD, DD, 31, 0);
}

// Round 4
// 213.328 us; speedup vs baseline: 1.3784x; 1.1556x over previous
//
#include <hip/hip_runtime.h>
#include <hip/hip_bf16.h>

// Problem constants (B=4, S=2048, D=1024, fp32 in/out)
#define BB 4
#define SS 2048
#define DD 1024

using f32x4  = __attribute__((ext_vector_type(4))) float;
using i32x4  = __attribute__((ext_vector_type(4))) int;
using i32x8  = __attribute__((ext_vector_type(8))) int;

struct f8_t { unsigned char b; };

// async global->LDS, 16B per lane. LDS dest = wave-uniform base + lane*16.
__device__ __forceinline__ void gld16(const void* g, void* l) {
    __builtin_amdgcn_global_load_lds(
        (const __attribute__((address_space(1))) void*)(g),
        (__attribute__((address_space(3))) void*)(l),
        16, 0, 0);
}

__device__ __forceinline__ void store1(float* p, float v) { *p = v; }
__device__ __forceinline__ void store1(f8_t* p, float v)  {
    p->b = (unsigned char)(__builtin_amdgcn_cvt_pk_fp8_f32(v, v, 0, false) & 0xff);
}

// ---------------------------------------------------------------------------
// x: fp32 -> fp8(e4m3), 8 elems/thread
// ---------------------------------------------------------------------------
__global__ void cvt_x_kernel(const float* __restrict__ x, unsigned char* __restrict__ x8, int n8) {
    int i = blockIdx.x * blockDim.x + threadIdx.x;
    if (i >= n8) return;
    float4 a = ((const float4*)x)[2 * i];
    float4 b = ((const float4*)x)[2 * i + 1];
    int lo = __builtin_amdgcn_cvt_pk_fp8_f32(a.x, a.y, 0, false);
    lo     = __builtin_amdgcn_cvt_pk_fp8_f32(a.z, a.w, lo, true);
    int hi = __builtin_amdgcn_cvt_pk_fp8_f32(b.x, b.y, 0, false);
    hi     = __builtin_amdgcn_cvt_pk_fp8_f32(b.z, b.w, hi, true);
    ((int2*)x8)[i] = make_int2(lo, hi);
}

// Wq,Wk,Wv -> fp8 contiguous. n8 = nw/8.
__global__ void cvt_w_kernel(const float* __restrict__ Wq, const float* __restrict__ Wk,
                             const float* __restrict__ Wv, unsigned char* __restrict__ w8, int n8) {
    int i = blockIdx.x * blockDim.x + threadIdx.x;
    int seg = i / n8;            // wave-uniform (n8 % 256 == 0)
    int j = i - seg * n8;
    const float* src = (seg == 0) ? Wq : (seg == 1) ? Wk : Wv;
    float4 a = ((const float4*)src)[2 * j];
    float4 b = ((const float4*)src)[2 * j + 1];
    int lo = __builtin_amdgcn_cvt_pk_fp8_f32(a.x, a.y, 0, false);
    lo     = __builtin_amdgcn_cvt_pk_fp8_f32(a.z, a.w, lo, true);
    int hi = __builtin_amdgcn_cvt_pk_fp8_f32(b.x, b.y, 0, false);
    hi     = __builtin_amdgcn_cvt_pk_fp8_f32(b.z, b.w, hi, true);
    ((int2*)(w8 + (size_t)seg * n8 * 8))[j] = make_int2(lo, hi);
}

// ---------------------------------------------------------------------------
// xsum[b][d] = sum_s x[b][s][d]  (fp32, exact). atomics over s-chunks.
// grid (16, 16): x = (b*4+dchunk), y = schunk of 128.
// ---------------------------------------------------------------------------
__global__ void xsum_kernel(const float* __restrict__ x, float* __restrict__ xsum) {
    int bd = blockIdx.x;
    int b  = bd >> 2, dc = bd & 3;
    int d  = dc * 256 + threadIdx.x;
    int s0 = blockIdx.y * 128;
    const float* p = x + ((size_t)b * SS + s0) * DD + d;
    float acc = 0.f;
    for (int i = 0; i < 128; ++i) acc += p[(size_t)i * DD];
    atomicAdd(&xsum[b * DD + d], acc);
}

// colsumV[b][c] = sum_d xsum[b][d] * Wv[c][d]   (one wave per output)
__global__ void colsumv_kernel(const float* __restrict__ Wv, const float* __restrict__ xsum,
                               float* __restrict__ colsum) {
    int idx  = blockIdx.x * 4 + (threadIdx.x >> 6);   // 0..4095
    int b    = idx >> 10, c = idx & 1023;
    int lane = threadIdx.x & 63;
    const float* wr = Wv + (size_t)c * DD;
    const float* xs = xsum + b * DD;
    float acc = 0.f;
#pragma unroll 4
    for (int d = lane; d < DD; d += 64) acc += wr[d] * xs[d];
#pragma unroll
    for (int off = 32; off; off >>= 1) acc += __shfl_xor(acc, off);
    if (lane == 0) colsum[idx] = acc;
}

// ---------------------------------------------------------------------------
// fp8 (e4m3) NT GEMM via MX-scaled MFMA 16x16x128. BK=128, 128x128 tile.
// XOR-8 LDS swizzle on the staging source. Epilogue modes:
//   0: plain store CT              (QK projection, fp8 out)
//   1: col-batch-split fp8 store   (V^T)
//   2: scores: t=exp(acc*qmask/32)-1; store fp8 512t; atomicAdd row sums of t
//   3: PV: out = (acc + colsumV[d]) / (2048 + rsum[q]), fp32; A-scale 2^-9
// ---------------------------------------------------------------------------
template <int MODE, typename CT>
__global__ __launch_bounds__(256, 3) void gemm_f8(
    const unsigned char* __restrict__ A, const unsigned char* __restrict__ B,
    CT* __restrict__ C, int M, int N, int K,
    long batchA, long batchB, long batchC,
    int ldc, int col_shift, long cstride,
    const float* __restrict__ qmask, float* __restrict__ rsum,
    const float* __restrict__ colsum) {
    constexpr int BM = 128, BN = 128, BK = 128;
    constexpr int SCALE_A = (MODE == 3) ? 118 : 127;   // 2^-9 un-scales T' = 512 t
    __shared__ __attribute__((aligned(16))) unsigned char As[BM * BK];
    __shared__ __attribute__((aligned(16))) unsigned char Bs[BN * BK];

    const int tid  = threadIdx.x;
    const int lane = tid & 63;
    const int wv   = tid >> 6;
    const int l16  = lane & 15;
    const int quad = lane >> 4;
    const int wm   = wv >> 1;
    const int wn   = wv & 1;

    const int m0 = blockIdx.y * BM;
    const int n0 = blockIdx.x * BN;
    const long z = blockIdx.z;
    const unsigned char* Ab = A + z * batchA;
    const unsigned char* Bb = B + z * batchB;

    const int sA = (2 * quad) ^ (l16 & 7);   // swizzled chunk (low 16B of frag)

    f32x4 acc[4][4] = {};

    for (int kt = 0; kt < K; kt += BK) {
#pragma unroll
        for (int j = 0; j < 4; ++j) {
            int slot = j * 256 + wv * 64 + lane;   // 0..1023
            int r = slot >> 3;
            int c = (slot & 7) ^ (r & 7);
            gld16(Ab + (size_t)(m0 + r) * K + (kt + c * 16),
                  As + (size_t)(j * 256 + wv * 64) * 16);
        }
#pragma unroll
        for (int j = 0; j < 4; ++j) {
            int slot = j * 256 + wv * 64 + lane;
            int r = slot >> 3;
            int c = (slot & 7) ^ (r & 7);
            gld16(Bb + (size_t)(n0 + r) * K + (kt + c * 16),
                  Bs + (size_t)(j * 256 + wv * 64) * 16);
        }
        asm volatile("s_waitcnt vmcnt(0)" ::: "memory");
        __syncthreads();

        i32x8 af[4], bfr[4];
#pragma unroll
        for (int i = 0; i < 4; ++i) {
            int r = wm * 64 + i * 16 + l16;
            i32x4 p0 = *(const i32x4*)(As + r * 128 + sA * 16);
            i32x4 p1 = *(const i32x4*)(As + r * 128 + (sA ^ 1) * 16);
            af[i][0]=p0[0]; af[i][1]=p0[1]; af[i][2]=p0[2]; af[i][3]=p0[3];
            af[i][4]=p1[0]; af[i][5]=p1[1]; af[i][6]=p1[2]; af[i][7]=p1[3];
        }
#pragma unroll
        for (int i = 0; i < 4; ++i) {
            int r = wn * 64 + i * 16 + l16;
            i32x4 p0 = *(const i32x4*)(Bs + r * 128 + sA * 16);
            i32x4 p1 = *(const i32x4*)(Bs + r * 128 + (sA ^ 1) * 16);
            bfr[i][0]=p0[0]; bfr[i][1]=p0[1]; bfr[i][2]=p0[2]; bfr[i][3]=p0[3];
            bfr[i][4]=p1[0]; bfr[i][5]=p1[1]; bfr[i][6]=p1[2]; bfr[i][7]=p1[3];
        }

#pragma unroll
        for (int i = 0; i < 4; ++i)
#pragma unroll
            for (int j = 0; j < 4; ++j)
                acc[i][j] = __builtin_amdgcn_mfma_scale_f32_16x16x128_f8f6f4(
                    af[i], bfr[j], acc[i][j], 0, 0, 0, SCALE_A, 0, 127);
        __syncthreads();
    }

    // ---------------- epilogue (C/D layout: col=lane&15, row=quad*4+reg) ----
    CT* Cb = C + z * batchC;

    if constexpr (MODE == 0) {
#pragma unroll
        for (int mi = 0; mi < 4; ++mi)
#pragma unroll
            for (int ni = 0; ni < 4; ++ni) {
                int colg = n0 + wn * 64 + ni * 16 + l16;
#pragma unroll
                for (int r = 0; r < 4; ++r) {
                    int rowg = m0 + wm * 64 + mi * 16 + quad * 4 + r;
                    store1(Cb + (size_t)rowg * ldc + colg, acc[mi][ni][r]);
                }
            }
    } else if constexpr (MODE == 1) {
#pragma unroll
        for (int mi = 0; mi < 4; ++mi)
#pragma unroll
            for (int ni = 0; ni < 4; ++ni) {
                int colg = n0 + wn * 64 + ni * 16 + l16;
                int cb   = colg >> col_shift;
                int ccol = colg - (cb << col_shift);
#pragma unroll
                for (int r = 0; r < 4; ++r) {
                    int rowg = m0 + wm * 64 + mi * 16 + quad * 4 + r;
                    store1(Cb + (long)cb * cstride + (size_t)rowg * ldc + ccol, acc[mi][ni][r]);
                }
            }
    } else if constexpr (MODE == 2) {
        const float* qm = qmask + (z << 11);
        float* rs = rsum + (z << 11);
#pragma unroll
        for (int mi = 0; mi < 4; ++mi) {
#pragma unroll
            for (int r = 0; r < 4; ++r) {
                int rowg = m0 + wm * 64 + mi * 16 + quad * 4 + r;
                float fac = qm[rowg] * 0.03125f;     // q_mask / sqrt(1024)
                float part = 0.f;
#pragma unroll
                for (int ni = 0; ni < 4; ++ni) {
                    int colg = n0 + wn * 64 + ni * 16 + l16;
                    float t = __expf(acc[mi][ni][r] * fac) - 1.0f;
                    part += t;
                    store1(Cb + (size_t)rowg * ldc + colg, t * 512.0f);
                }
                // reduce over the 16 lanes sharing this row (l16 group)
                part += __shfl_xor(part, 1);
                part += __shfl_xor(part, 2);
                part += __shfl_xor(part, 4);
                part += __shfl_xor(part, 8);
                if (l16 == 0) atomicAdd(&rs[rowg], part);
            }
        }
    } else {  // MODE == 3
        const float* rs = rsum + (z << 11);
        const float* cs = colsum + (z << 10);
#pragma unroll
        for (int mi = 0; mi < 4; ++mi) {
#pragma unroll
            for (int r = 0; r < 4; ++r) {
                int rowg = m0 + wm * 64 + mi * 16 + quad * 4 + r;
                float inv = 1.0f / (2048.0f + rs[rowg]);
#pragma unroll
                for (int ni = 0; ni < 4; ++ni) {
                    int colg = n0 + wn * 64 + ni * 16 + l16;
                    store1(Cb + (size_t)rowg * ldc + colg, (acc[mi][ni][r] + cs[colg]) * inv);
                }
            }
        }
    }
}

// ---------------------------------------------------------------------------
extern "C" void kernel_launch(void* const* d_in, const int* in_sizes, int n_in,
                              void* d_out, int out_size, void* d_ws, size_t ws_size,
                              hipStream_t stream) {
    const float* x     = (const float*)d_in[0];
    const float* Wq    = (const float*)d_in[1];
    const float* Wk    = (const float*)d_in[2];
    const float* Wv    = (const float*)d_in[3];
    const float* qmask = (const float*)d_in[4];
    float* out = (float*)d_out;

    const long nx = (long)BB * SS * DD;   // 8,388,608
    const long nw = (long)DD * DD;        // 1,048,576

    unsigned char* ws  = (unsigned char*)d_ws;
    unsigned char* x8  = ws;                          // x fp8         8.4 MB
    unsigned char* w8  = x8 + nx;                     // Wq,Wk,Wv fp8  3 MB
    unsigned char* qk8 = w8 + 3 * nw;                 // Q,K fp8       16.8 MB
    unsigned char* vt8 = qk8 + 2 * nx;                // V^T fp8 (B,D,S) 8.4 MB
    unsigned char* t8  = vt8 + nx;                    // T = 512(exp-1) fp8 (B,S,S) 16.8 MB
    float* xsum   = (float*)(t8 + (long)BB * SS * SS);// (B,D) 16 KB
    float* rs     = xsum + BB * DD;                   // (B,S) 32 KB  (Σt per row)
    float* colsum = rs + BB * SS;                     // (B,D) 16 KB

    // 0. zero the accumulators (xsum and rs are adjacent)
    hipMemsetAsync(xsum, 0, (size_t)(BB * DD + BB * SS) * sizeof(float), stream);

    // 1. conversions + exact colsum(V) path
    cvt_x_kernel<<<dim3((int)(nx / 8 / 256)), dim3(256), 0, stream>>>(x, x8, (int)(nx / 8));
    cvt_w_kernel<<<dim3((int)(3 * nw / 8 / 256)), dim3(256), 0, stream>>>(Wq, Wk, Wv, w8, (int)(nw / 8));
    xsum_kernel<<<dim3(16, 16), dim3(256), 0, stream>>>(x, xsum);
    colsumv_kernel<<<dim3(1024), dim3(256), 0, stream>>>(Wv, xsum, colsum);

    // 2. Q = x@Wq^T, K = x@Wk^T  (fp8 MX GEMM, z=2, fp8 out)
    gemm_f8<0, f8_t><<<dim3(DD / 128, (BB * SS) / 128, 2), 256, 0, stream>>>(
        x8, w8, (f8_t*)qk8, BB * SS, DD, DD, 0, nw, nx, DD, 31, 0, nullptr, nullptr, nullptr);

    // 3. V^T = Wv @ x^T -> (B, D, S) fp8, col-batch-split store
    gemm_f8<1, f8_t><<<dim3((BB * SS) / 128, DD / 128, 1), 256, 0, stream>>>(
        w8 + 2 * nw, x8, (f8_t*)vt8, DD, BB * SS, DD, 0, 0, 0, SS, 11, (long)DD * SS,
        nullptr, nullptr, nullptr);

    // 4. T = exp(mask*scores)-1 (x512, fp8) + row sums of t (atomics)
    gemm_f8<2, f8_t><<<dim3(SS / 128, SS / 128, BB), 256, 0, stream>>>(
        qk8, qk8 + nx, (f8_t*)t8, SS, SS, DD, (long)SS * DD, (long)SS * DD, (long)SS * SS,
        SS, 31, 0, qmask, rs, nullptr);

    // 5. out = (T@V * 2^-9 + colsumV) / (2048 + rowsum_t), fp32
    gemm_f8<3, float><<<dim3(DD / 128, SS / 128, BB), 256, 0, stream>>>(
        t8, vt8, out, SS, DD, SS, (long)SS * SS, (long)DD * SS, (long)SS * DD,
        DD, 31, 0, nullptr, rs, colsum);
}